// Round 21
// baseline (597.601 us; speedup 1.0000x reference)
//
#include <hip/hip_runtime.h>
#include <stdint.h>

#pragma clang fp contract(off)

#define B 8
#define N 65536
#define KC 64        // clusters
#define M 128        // neighbors per center (NPOINT/K*2)
#define S 64         // fps samples per group (NPOINT/K)
#define NITER 10
#define HPAD 257             // padded per-wave histogram stride
#define SAMPLE 8192          // prefix sample size for threshold
#define SCAP 2048            // sample same-byte candidate cap (u32 keys)
#define CAPG 3072            // per-(b,k) global candidate cap
#define WCAP 512             // winners buffer (pow2), >= M
#define CSTRIDE 32           // cnt counter stride in u32 (128 B -> 1 per cache line)
#define NCHK 64              // chunks per batch in k_assign (1024 points each)
#define UPD_T 1024           // threads per cluster-update block
#define RANGE 32768          // points per scan range in cluster update
#define NRANGE (N / RANGE)   // 2
#define PPT (RANGE / UPD_T)  // 32 points per thread
#define GBATCH 2048          // members gathered per sub-batch

using u32 = unsigned int;
using u64 = unsigned long long;
using u16 = unsigned short;

// ---- exact fp32 helpers (no FMA contraction, fixed association) ----
__device__ __forceinline__ float sq3(float a, float b, float c) {
  return __fadd_rn(__fadd_rn(__fmul_rn(a, a), __fmul_rn(b, b)), __fmul_rn(c, c));
}
__device__ __forceinline__ float dot3(float x0, float x1, float x2,
                                      float c0, float c1, float c2) {
  return __fadd_rn(__fadd_rn(__fmul_rn(x0, c0), __fmul_rn(x1, c1)), __fmul_rn(x2, c2));
}
__device__ __forceinline__ float distf(float s2, float d2, float dt) {
  return __fsub_rn(__fadd_rn(s2, d2), __fmul_rn(2.0f, dt));
}
// monotone float->uint key (total order preserving)
__device__ __forceinline__ u32 fkey(float f) {
  u32 u = __float_as_uint(f);
  return (u & 0x80000000u) ? ~u : (u | 0x80000000u);
}

// ---- kernels ----

__global__ void k_init_centers(const float* __restrict__ x, float* __restrict__ centers) {
  int i = blockIdx.x * blockDim.x + threadIdx.x;
  if (i >= B * KC * 3) return;
  int b = i / (KC * 3);
  int r = i % (KC * 3);
  centers[i] = x[(size_t)b * N * 3 + r];   // c = x[:, :K, :]
}

// 4 points per thread via 3x float4 loads, packed u32 cl store.
// XCD-affine: batch = blockIdx & 7.
__global__ __launch_bounds__(256)
void k_assign(const float* __restrict__ x, const float* __restrict__ centers,
              unsigned char* __restrict__ cl) {
  __shared__ float4 cs[KC];
  int g = blockIdx.x;
  int b = g & 7;                    // batch -> XCD
  int chunk = g >> 3;               // 0..63
  int t = threadIdx.x;
  if (t < KC) {
    float a0 = centers[(b * KC + t) * 3 + 0];
    float a1 = centers[(b * KC + t) * 3 + 1];
    float a2 = centers[(b * KC + t) * 3 + 2];
    cs[t] = make_float4(a0, a1, a2, sq3(a0, a1, a2));
  }
  __syncthreads();
  int q = chunk * 256 + t;          // quad index (points 4q..4q+3)
  const float4* xb4 = (const float4*)(x + (size_t)b * N * 3);
  float4 A = xb4[3 * q], Bv = xb4[3 * q + 1], C = xb4[3 * q + 2];
  float p0x = A.x, p0y = A.y, p0z = A.z;
  float p1x = A.w, p1y = Bv.x, p1z = Bv.y;
  float p2x = Bv.z, p2y = Bv.w, p2z = C.x;
  float p3x = C.y, p3y = C.z, p3z = C.w;
  float s0 = sq3(p0x, p0y, p0z);
  float s1 = sq3(p1x, p1y, p1z);
  float s2 = sq3(p2x, p2y, p2z);
  float s3 = sq3(p3x, p3y, p3z);
  float inf = __int_as_float(0x7f800000);
  float b0 = inf, b1 = inf, b2 = inf, b3 = inf;
  int i0 = 0, i1 = 0, i2 = 0, i3 = 0;
  for (int k = 0; k < KC; ++k) {
    float4 cc = cs[k];
    float d0 = distf(s0, cc.w, dot3(p0x, p0y, p0z, cc.x, cc.y, cc.z));
    float d1 = distf(s1, cc.w, dot3(p1x, p1y, p1z, cc.x, cc.y, cc.z));
    float d2 = distf(s2, cc.w, dot3(p2x, p2y, p2z, cc.x, cc.y, cc.z));
    float d3 = distf(s3, cc.w, dot3(p3x, p3y, p3z, cc.x, cc.y, cc.z));
    if (d0 < b0) { b0 = d0; i0 = k; }   // first-min == argmin
    if (d1 < b1) { b1 = d1; i1 = k; }
    if (d2 < b2) { b2 = d2; i2 = k; }
    if (d3 < b3) { b3 = d3; i3 = k; }
  }
  *(u32*)(cl + (size_t)b * N + 4 * q) =
      (u32)i0 | ((u32)i1 << 8) | ((u32)i2 << 16) | ((u32)i3 << 24);
}

// one block per (b,k), 1024 threads, TWO 32K ranges (halves barrier count
// vs 4 ranges): scan cl (stable ascending order), build u16 member list in
// LDS, gather coords to SoA LDS, lanes 0/1/2 run the three sequential fp32
// chains (scalar + unroll 8, R14-proven) — bit-identical to np.add.at.
__global__ __launch_bounds__(UPD_T)
void k_cluster_update(const float* __restrict__ x, const unsigned char* __restrict__ cl,
                      float* __restrict__ centers) {
  __shared__ u16 midx[RANGE];                  // 64 KB
  __shared__ float bcoord[3][GBATCH + 1];      // 24.6 KB, SoA, padded
  __shared__ int woff[16];
  __shared__ int sTot;
  int g = blockIdx.x;
  int bk = ((g & 7) << 6) | (g >> 3);          // XCD-affine: batch = g & 7
  int b = bk >> 6, k = bk & 63;
  int t = threadIdx.x, lane = t & 63, wid = t >> 6;
  const unsigned char* clb = cl + (size_t)b * N;
  const float* xb = x + (size_t)b * N * 3;
  float acc = 0.f;      // lanes 0/1/2 of wave 0 carry x/y/z chains
  int cntAll = 0;

  for (int r = 0; r < NRANGE; ++r) {
    // 1. scan my contiguous 32-point segment (2x uint4)
    const uint4* cp = (const uint4*)(clb + r * RANGE) + t * 2;
    uint4 v0 = cp[0], v1 = cp[1];
    u32 wsv[8] = {v0.x, v0.y, v0.z, v0.w, v1.x, v1.y, v1.z, v1.w};
    int m = 0;
#pragma unroll
    for (int j = 0; j < PPT; ++j)
      m += (((wsv[j >> 2] >> ((j & 3) * 8)) & 255u) == (u32)k);
    // 2. wave inclusive scan
    int incl = m;
#pragma unroll
    for (int o = 1; o < 64; o <<= 1) {
      int u = __shfl_up(incl, o);
      if (lane >= o) incl += u;
    }
    if (lane == 63) woff[wid] = incl;
    __syncthreads();
    // 3. parallel 16-lane combine (wave 0)
    if (t < 16) {
      int vv = woff[t];
      int inc2 = vv;
#pragma unroll
      for (int o = 1; o < 16; o <<= 1) {
        int u = __shfl_up(inc2, o);
        if (t >= o) inc2 += u;
      }
      woff[t] = inc2 - vv;     // exclusive
      if (t == 15) sTot = inc2;
    }
    __syncthreads();
    int off = woff[wid] + incl - m;
    int tot = sTot;
    // 4. write member local indices in ascending order (stable)
    int base = t * PPT;
#pragma unroll
    for (int j = 0; j < PPT; ++j) {
      if (((wsv[j >> 2] >> ((j & 3) * 8)) & 255u) == (u32)k)
        midx[off++] = (u16)(base + j);
    }
    __syncthreads();
    // 5. gather + chain in batches
    int rbase = r * RANGE;
    for (int bo = 0; bo < tot; bo += GBATCH) {
      int bn = min(GBATCH, tot - bo);
      for (int i = t; i < bn; i += UPD_T) {
        int li = rbase + (int)midx[bo + i];
        size_t src = (size_t)li * 3;
        bcoord[0][i] = xb[src];
        bcoord[1][i] = xb[src + 1];
        bcoord[2][i] = xb[src + 2];
      }
      __syncthreads();
      if (t < 3) {
        const float* bb = &bcoord[t][0];
#pragma unroll 8
        for (int i = 0; i < bn; ++i) acc = __fadd_rn(acc, bb[i]);
      }
      __syncthreads();
    }
    cntAll += tot;
    __syncthreads();
  }
  if (t < 3) centers[bk * 3 + t] = __fdiv_rn(acc, (float)cntAll);
}

// ---- top-k stage 1: per-(b,k) EXACT sample threshold ----
__global__ __launch_bounds__(256)
void k_thresh(const float* __restrict__ x, const float* __restrict__ centers,
              u32* __restrict__ thr, u32* __restrict__ cnt) {
  __shared__ u32 whist[4 * HPAD];
  __shared__ int sv[256];
  __shared__ u32 skeys[SCAP];
  __shared__ float4 scen;
  __shared__ u32 sSel;
  __shared__ int sNeed, sCntBin, sNum;
  int g = blockIdx.x;
  int bk = ((g & 7) << 6) | (g >> 3);   // XCD-affine
  int b = bk >> 6;
  int t = threadIdx.x, wid = t >> 6;
  if (t == 0) {
    float c0 = centers[bk * 3], c1 = centers[bk * 3 + 1], c2 = centers[bk * 3 + 2];
    scen = make_float4(c0, c1, c2, sq3(c0, c1, c2));
    cnt[bk * CSTRIDE] = 0;
    sNum = 0;
  }
  for (int i = t; i < 4 * HPAD; i += 256) whist[i] = 0;
  __syncthreads();
  float c0 = scen.x, c1 = scen.y, c2 = scen.z, d2 = scen.w;
  const float2* xb2 = (const float2*)(x + (size_t)b * N * 3);

  for (int p = t; p < SAMPLE / 2; p += 256) {
    float2 A = xb2[3 * p], Bv = xb2[3 * p + 1], C = xb2[3 * p + 2];
    float d0 = distf(sq3(A.x, A.y, Bv.x), d2, dot3(A.x, A.y, Bv.x, c0, c1, c2));
    float d1 = distf(sq3(Bv.y, C.x, C.y), d2, dot3(Bv.y, C.x, C.y, c0, c1, c2));
    atomicAdd(&whist[wid * HPAD + (fkey(d0) >> 24)], 1u);
    atomicAdd(&whist[wid * HPAD + (fkey(d1) >> 24)], 1u);
  }
  __syncthreads();
  int own = (int)(whist[0 * HPAD + t] + whist[1 * HPAD + t] +
                  whist[2 * HPAD + t] + whist[3 * HPAD + t]);
  sv[t] = own;
  __syncthreads();
  for (int off = 1; off < 256; off <<= 1) {
    int add = (t >= off) ? sv[t - off] : 0;
    __syncthreads();
    sv[t] += add;
    __syncthreads();
  }
  if (sv[t] >= M && sv[t] - own < M) {
    sSel = (u32)t; sNeed = M - (sv[t] - own); sCntBin = own;
  }
  __syncthreads();
  u32 selByte = sSel;
  int need = sNeed;
  int cntBin = sCntBin;
  u32 prefix = selByte << 24;

  if (cntBin <= SCAP) {
    for (int p = t; p < SAMPLE / 2; p += 256) {
      float2 A = xb2[3 * p], Bv = xb2[3 * p + 1], C = xb2[3 * p + 2];
      float d0 = distf(sq3(A.x, A.y, Bv.x), d2, dot3(A.x, A.y, Bv.x, c0, c1, c2));
      float d1 = distf(sq3(Bv.y, C.x, C.y), d2, dot3(Bv.y, C.x, C.y, c0, c1, c2));
      u32 k0 = fkey(d0), k1 = fkey(d1);
      if ((k0 >> 24) == selByte) skeys[atomicAdd(&sNum, 1)] = k0;
      if ((k1 >> 24) == selByte) skeys[atomicAdd(&sNum, 1)] = k1;
    }
    __syncthreads();
    int ne = sNum;
    for (int sh = 16; sh >= 0; sh -= 8) {
      whist[t] = 0;
      __syncthreads();
      for (int i = t; i < ne; i += 256) {
        u32 kkk = skeys[i];
        if ((kkk >> (sh + 8)) == (prefix >> (sh + 8)))
          atomicAdd(&whist[(kkk >> sh) & 255u], 1u);
      }
      __syncthreads();
      int own2 = (int)whist[t];
      sv[t] = own2;
      __syncthreads();
      for (int off = 1; off < 256; off <<= 1) {
        int add = (t >= off) ? sv[t - off] : 0;
        __syncthreads();
        sv[t] += add;
        __syncthreads();
      }
      if (sv[t] >= need && sv[t] - own2 < need) {
        sSel = prefix | ((u32)t << sh);
        sNeed = need - (sv[t] - own2);
      }
      __syncthreads();
      prefix = sSel; need = sNeed;
      __syncthreads();
    }
    if (t == 0) thr[bk] = prefix;
  } else {
    if (t == 0) thr[bk] = prefix | 0x00FFFFFFu;
  }
}

// ---- top-k stage 2: one shared pass, ballot-aggregated reservation ----
__global__ __launch_bounds__(256)
void k_scatter_test(const float* __restrict__ x, const float* __restrict__ centers,
                    const u32* __restrict__ thr, u32* __restrict__ cnt,
                    u32* __restrict__ cand) {
  __shared__ float4 cs[KC];
  __shared__ u32 lthr[KC];
  __shared__ u64 wm0[4][KC], wm1[4][KC];
  __shared__ u32 wbase[4][KC];
  int g = blockIdx.x;
  int b = g & 7;
  int chunk = g >> 3;
  int t = threadIdx.x, lane = t & 63, wid = t >> 6;
  if (t < KC) {
    float a0 = centers[(b * KC + t) * 3 + 0];
    float a1 = centers[(b * KC + t) * 3 + 1];
    float a2 = centers[(b * KC + t) * 3 + 2];
    cs[t] = make_float4(a0, a1, a2, sq3(a0, a1, a2));
    lthr[t] = thr[b * KC + t];
  }
  __syncthreads();
  int pr = chunk * 256 + t;
  const float2* xb2 = (const float2*)(x + (size_t)b * N * 3);
  float2 A = xb2[3 * pr], Bv = xb2[3 * pr + 1], C = xb2[3 * pr + 2];
  float s20 = sq3(A.x, A.y, Bv.x);
  float s21 = sq3(Bv.y, C.x, C.y);
  u32 n0 = 2 * pr, n1 = 2 * pr + 1;
  u64 ltm = ((u64)1 << lane) - 1;

  for (int k = 0; k < KC; ++k) {
    float4 cc = cs[k];
    float d0 = distf(s20, cc.w, dot3(A.x, A.y, Bv.x, cc.x, cc.y, cc.z));
    float d1 = distf(s21, cc.w, dot3(Bv.y, C.x, C.y, cc.x, cc.y, cc.z));
    u64 m0 = __ballot(fkey(d0) <= lthr[k]);
    u64 m1 = __ballot(fkey(d1) <= lthr[k]);
    if (lane == 0) { wm0[wid][k] = m0; wm1[wid][k] = m1; }
  }
  __syncthreads();
  if (t < KC) {
    u32 pc[4];
    u32 total = 0;
#pragma unroll
    for (int w = 0; w < 4; ++w) {
      pc[w] = (u32)(__popcll(wm0[w][t]) + __popcll(wm1[w][t]));
      total += pc[w];
    }
    u32 base = (total > 0) ? atomicAdd(&cnt[(b * KC + t) * CSTRIDE], total) : 0u;
#pragma unroll
    for (int w = 0; w < 4; ++w) { wbase[w][t] = base; base += pc[w]; }
  }
  __syncthreads();
  u64 mybit = (u64)1 << lane;
  for (int k = 0; k < KC; ++k) {
    u64 m0 = wm0[wid][k], m1 = wm1[wid][k];
    if ((m0 | m1) == 0) continue;
    u32 wb = wbase[wid][k];
    u32* cb = cand + (size_t)(b * KC + k) * CAPG;
    if (m0 & mybit) {
      u32 pos = wb + (u32)__popcll(m0 & ltm);
      if (pos < CAPG) cb[pos] = n0;
    }
    if (m1 & mybit) {
      u32 pos = wb + (u32)__popcll(m0) + (u32)__popcll(m1 & ltm);
      if (pos < CAPG) cb[pos] = n1;
    }
  }
}

// ---- top-k stage 3: radix-select exact 128th key, sort winners ----
__global__ __launch_bounds__(256)
void k_topk_sort(const float* __restrict__ x, const float* __restrict__ centers,
                 const u32* __restrict__ cnt, const u32* __restrict__ cand,
                 float* __restrict__ neighbor) {
  __shared__ u64 candList[CAPG];
  __shared__ u32 hist[256];
  __shared__ u64 wbuf[WCAP];
  __shared__ u64 lessList[M];
  __shared__ u32 eqList[256];
  __shared__ u32 sSel;
  __shared__ int sNeed;
  __shared__ int cntW, cntLess, cntEq;
  __shared__ float4 scen;
  int g = blockIdx.x;
  int bk = ((g & 7) << 6) | (g >> 3);
  int b = bk >> 6;
  int t = threadIdx.x, lane = t & 63, wid = t >> 6;
  if (t == 0) {
    float c0 = centers[bk * 3], c1 = centers[bk * 3 + 1], c2 = centers[bk * 3 + 2];
    scen = make_float4(c0, c1, c2, sq3(c0, c1, c2));
    cntW = 0;
  }
  __syncthreads();
  float c0 = scen.x, c1 = scen.y, c2 = scen.z, d2 = scen.w;
  const float* xb = x + (size_t)b * N * 3;
  int cc = (int)cnt[bk * CSTRIDE];

  if (cc <= CAPG) {
    const u32* cb = cand + (size_t)bk * CAPG;
    for (int i = t; i < cc; i += 256) {
      u32 n = cb[i];
      float x0 = xb[n * 3], x1 = xb[n * 3 + 1], x2 = xb[n * 3 + 2];
      float d = distf(sq3(x0, x1, x2), d2, dot3(x0, x1, x2, c0, c1, c2));
      candList[i] = ((u64)fkey(d) << 32) | n;
    }
    __syncthreads();
    u32 prefix = 0;
    int need = M;
    for (int r = 3; r >= 0; --r) {
      int sh = r * 8;
      hist[t] = 0;
      __syncthreads();
      for (int i = t; i < cc; i += 256) {
        u32 key = (u32)(candList[i] >> 32);
        bool ok = (r == 3) || ((key >> (sh + 8)) == (prefix >> (sh + 8)));
        if (ok) atomicAdd(&hist[(key >> sh) & 255u], 1u);
      }
      __syncthreads();
      if (wid == 0) {
        u32 h0 = hist[4 * lane + 0], h1 = hist[4 * lane + 1];
        u32 h2 = hist[4 * lane + 2], h3 = hist[4 * lane + 3];
        u32 lsum = h0 + h1 + h2 + h3;
        u32 incl = lsum;
#pragma unroll
        for (int o = 1; o < 64; o <<= 1) {
          u32 u = __shfl_up(incl, o);
          if (lane >= o) incl += u;
        }
        u32 excl = incl - lsum;
        if ((int)excl < need && need <= (int)incl) {
          u32 hh[4] = {h0, h1, h2, h3};
          u32 cum = excl; int bin = -1; u32 bc = 0;
#pragma unroll
          for (int j = 0; j < 4; ++j) {
            if (bin < 0 && (int)(cum + hh[j]) >= need) { bin = 4 * lane + j; bc = cum; }
            cum += hh[j];
          }
          sSel = prefix | ((u32)bin << sh);
          sNeed = need - (int)bc;
        }
      }
      __syncthreads();
      prefix = sSel; need = sNeed;
      __syncthreads();
    }
    u32 K128 = prefix;
    for (int i = t; i < cc; i += 256) {
      u64 e = candList[i];
      if ((u32)(e >> 32) <= K128) {
        int p = atomicAdd(&cntW, 1);
        if (p < WCAP) wbuf[p] = e;
      }
    }
    __syncthreads();
    int wcnt2 = cntW;
    if (wcnt2 <= WCAP) {
      for (int i = t; i < WCAP; i += 256) if (i >= wcnt2) wbuf[i] = ~0ull;
      __syncthreads();
      for (int ksz = 2; ksz <= WCAP; ksz <<= 1) {
        for (int j = ksz >> 1; j > 0; j >>= 1) {
          for (int idx = t; idx < WCAP; idx += 256) {
            int ixj = idx ^ j;
            if (ixj > idx) {
              u64 a = wbuf[idx], bb = wbuf[ixj];
              bool up = ((idx & ksz) == 0);
              if (up ? (a > bb) : (a < bb)) { wbuf[idx] = bb; wbuf[ixj] = a; }
            }
          }
          __syncthreads();
        }
      }
      if (t < M) {
        int idx = (int)(wbuf[t] & 0xFFFFFFFFu);
        size_t src = ((size_t)b * N + idx) * 3;
        size_t dst = ((size_t)bk * M + t) * 3;
        neighbor[dst]     = x[src];
        neighbor[dst + 1] = x[src + 1];
        neighbor[dst + 2] = x[src + 2];
      }
      return;
    }
  }

  // ---- fallback: full byte-radix over N (bit-identical, rare) ----
  if (t == 0) { cntLess = 0; cntEq = 0; }
  __syncthreads();
  u32 prefix = 0;
  int need = M;
  for (int r = 3; r >= 0; --r) {
    for (int i = t; i < 256; i += 256) hist[i] = 0;
    __syncthreads();
    int sh = r * 8;
    for (int n = t; n < N; n += 256) {
      float x0 = xb[n * 3], x1 = xb[n * 3 + 1], x2 = xb[n * 3 + 2];
      float d = distf(sq3(x0, x1, x2), d2, dot3(x0, x1, x2, c0, c1, c2));
      u32 key = fkey(d);
      bool ok = (r == 3) || ((key >> (sh + 8)) == (prefix >> (sh + 8)));
      if (ok) atomicAdd(&hist[(key >> sh) & 255u], 1u);
    }
    __syncthreads();
    if (t == 0) {
      int cum = 0;
      for (int bin = 0; bin < 256; ++bin) {
        int ccv = (int)hist[bin];
        if (cum + ccv >= need) { sSel = prefix | ((u32)bin << sh); sNeed = need - cum; break; }
        cum += ccv;
      }
    }
    __syncthreads();
    prefix = sSel; need = sNeed;
    __syncthreads();
  }
  u32 K128 = prefix;

  for (int n = t; n < N; n += 256) {
    float x0 = xb[n * 3], x1 = xb[n * 3 + 1], x2 = xb[n * 3 + 2];
    float d = distf(sq3(x0, x1, x2), d2, dot3(x0, x1, x2, c0, c1, c2));
    u32 key = fkey(d);
    if (key < K128) {
      int p = atomicAdd(&cntLess, 1);
      if (p < M) lessList[p] = ((u64)key << 32) | (u32)n;
    } else if (key == K128) {
      int p = atomicAdd(&cntEq, 1);
      if (p < 256) eqList[p] = (u32)n;
    }
  }
  __syncthreads();
  int nl = cntLess;
  int ne2 = cntEq;
  for (int i = t; i < M; i += 256) if (i >= nl) lessList[i] = ~0ull;
  for (int i = t; i < 256; i += 256) if (i >= ne2) eqList[i] = 0xFFFFFFFFu;
  __syncthreads();

  for (int ksz = 2; ksz <= M; ksz <<= 1) {
    for (int j = ksz >> 1; j > 0; j >>= 1) {
      for (int idx = t; idx < M; idx += 256) {
        int ixj = idx ^ j;
        if (ixj > idx) {
          u64 a = lessList[idx], bb = lessList[ixj];
          bool up = ((idx & ksz) == 0);
          if (up ? (a > bb) : (a < bb)) { lessList[idx] = bb; lessList[ixj] = a; }
        }
      }
      __syncthreads();
    }
  }
  for (int ksz = 2; ksz <= 256; ksz <<= 1) {
    for (int j = ksz >> 1; j > 0; j >>= 1) {
      for (int idx = t; idx < 256; idx += 256) {
        int ixj = idx ^ j;
        if (ixj > idx) {
          u32 a = eqList[idx], bb = eqList[ixj];
          bool up = ((idx & ksz) == 0);
          if (up ? (a > bb) : (a < bb)) { eqList[idx] = bb; eqList[ixj] = a; }
        }
      }
      __syncthreads();
    }
  }

  if (t < M) {
    int idx = (t < nl) ? (int)(lessList[t] & 0xFFFFFFFFu) : (int)eqList[t - nl];
    size_t src = ((size_t)b * N + idx) * 3;
    size_t dst = ((size_t)bk * M + t) * 3;
    neighbor[dst]     = x[src];
    neighbor[dst + 1] = x[src + 1];
    neighbor[dst + 2] = x[src + 2];
  }
}

// wave-synchronous FPS: 1 wave per group, 2 points/lane, packed-u64
// shfl_xor argmax (first-occurrence tiebreak), zero in-loop barriers.
__global__ __launch_bounds__(64)
void k_fps(const float* __restrict__ neighbor, const int* __restrict__ farthest0,
           const float* __restrict__ centers, float* __restrict__ out) {
  __shared__ float4 pts[M];
  int bg = blockIdx.x;
  int b = bg >> 6, g = bg & 63;
  int t = threadIdx.x;
  {
    int i = bg * 64 + t;
    if (i < B * KC * 3) out[B * 4096 * 3 + i] = centers[i];
  }
  const float* nb = neighbor + (size_t)bg * M * 3;
  float ax = nb[6 * t],     ay = nb[6 * t + 1], az = nb[6 * t + 2];
  float bx = nb[6 * t + 3], by = nb[6 * t + 4], bz = nb[6 * t + 5];
  pts[2 * t]     = make_float4(ax, ay, az, 0.f);
  pts[2 * t + 1] = make_float4(bx, by, bz, 0.f);
  int far = farthest0[bg];
  float dist0 = 1e10f, dist1 = 1e10f;
  __syncthreads();
  float* ob = out + ((size_t)b * 4096 + g * 64) * 3;
  for (int s = 0; s < S; ++s) {
    if ((far >> 1) == t) {
      if (far & 1) { ob[3 * s] = bx; ob[3 * s + 1] = by; ob[3 * s + 2] = bz; }
      else         { ob[3 * s] = ax; ob[3 * s + 1] = ay; ob[3 * s + 2] = az; }
    }
    float4 cc = pts[far];
    float d0 = sq3(__fsub_rn(ax, cc.x), __fsub_rn(ay, cc.y), __fsub_rn(az, cc.z));
    float d1 = sq3(__fsub_rn(bx, cc.x), __fsub_rn(by, cc.y), __fsub_rn(bz, cc.z));
    dist0 = fminf(dist0, d0);
    dist1 = fminf(dist1, d1);
    u64 k0 = ((u64)__float_as_uint(dist0) << 32) | (u32)(M - 1 - 2 * t);
    u64 k1 = ((u64)__float_as_uint(dist1) << 32) | (u32)(M - 2 - 2 * t);
    u64 key = (k0 > k1) ? k0 : k1;
#pragma unroll
    for (int off = 1; off < 64; off <<= 1) {
      u64 o = __shfl_xor(key, off);
      if (o > key) key = o;
    }
    far = M - 1 - (int)(key & 0xFFFFFFFFu);
  }
}

extern "C" void kernel_launch(void* const* d_in, const int* in_sizes, int n_in,
                              void* d_out, int out_size, void* d_ws, size_t ws_size,
                              hipStream_t stream) {
  const float* x = (const float*)d_in[0];
  const int* farthest0 = (const int*)d_in[1];
  float* out = (float*)d_out;

  char* w = (char*)d_ws;
  float* centers  = (float*)(w);                               // 8 KB slot
  unsigned char* cl = (unsigned char*)(w + 8192);              // 512 KB
  u32* thr        = (u32*)(w + 8192 + 524288);                 // 4 KB slot
  u32* cnt        = (u32*)(w + 8192 + 524288 + 4096);          // 64 KB (strided)
  float* neighbor = (float*)(w + 8192 + 524288 + 4096 + 65536);            // 768 KB
  u32* cand       = (u32*)(w + 8192 + 524288 + 4096 + 65536 + 786432);     // 6 MB
  // total ws use ≈ 7.4 MB

  k_init_centers<<<6, 256, 0, stream>>>(x, centers);
  for (int it = 0; it < NITER; ++it) {
    k_assign<<<B * NCHK, 256, 0, stream>>>(x, centers, cl);
    k_cluster_update<<<B * KC, UPD_T, 0, stream>>>(x, cl, centers);
  }
  k_thresh<<<B * KC, 256, 0, stream>>>(x, centers, thr, cnt);
  k_scatter_test<<<B * NCHK * 2, 256, 0, stream>>>(x, centers, thr, cnt, cand);
  k_topk_sort<<<B * KC, 256, 0, stream>>>(x, centers, cnt, cand, neighbor);
  k_fps<<<B * KC, M / 2, 0, stream>>>(neighbor, farthest0, centers, out);
}

// Round 22
// 473.255 us; speedup vs baseline: 1.2627x; 1.2627x over previous
//
#include <hip/hip_runtime.h>
#include <stdint.h>

#pragma clang fp contract(off)

#define B 8
#define N 65536
#define KC 64        // clusters
#define M 128        // neighbors per center (NPOINT/K*2)
#define S 64         // fps samples per group (NPOINT/K)
#define NITER 10
#define HPAD 257             // padded per-wave histogram stride
#define SAMPLE 8192          // prefix sample size for threshold
#define SCAP 2048            // sample same-byte candidate cap (u32 keys)
#define CAPG 3072            // per-(b,k) global candidate cap
#define WCAP 512             // winners buffer (pow2), >= M
#define CSTRIDE 32           // cnt counter stride in u32 (128 B -> 1 per cache line)
#define NCHK 64              // chunks per batch in k_assign (1024 points each)
#define UPD_T 1024           // threads per cluster-update block
#define RANGE 16384          // points per scan range in cluster update
#define NRANGE (N / RANGE)   // 4
#define PPT (RANGE / UPD_T)  // 16 points per thread
#define GBATCH 2048          // members gathered per sub-batch

using u32 = unsigned int;
using u64 = unsigned long long;
using u16 = unsigned short;

// ---- exact fp32 helpers (no FMA contraction, fixed association) ----
__device__ __forceinline__ float sq3(float a, float b, float c) {
  return __fadd_rn(__fadd_rn(__fmul_rn(a, a), __fmul_rn(b, b)), __fmul_rn(c, c));
}
__device__ __forceinline__ float dot3(float x0, float x1, float x2,
                                      float c0, float c1, float c2) {
  return __fadd_rn(__fadd_rn(__fmul_rn(x0, c0), __fmul_rn(x1, c1)), __fmul_rn(x2, c2));
}
__device__ __forceinline__ float distf(float s2, float d2, float dt) {
  return __fsub_rn(__fadd_rn(s2, d2), __fmul_rn(2.0f, dt));
}
// monotone float->uint key (total order preserving)
__device__ __forceinline__ u32 fkey(float f) {
  u32 u = __float_as_uint(f);
  return (u & 0x80000000u) ? ~u : (u | 0x80000000u);
}

// ---- kernels ----

__global__ void k_init_centers(const float* __restrict__ x, float* __restrict__ centers) {
  int i = blockIdx.x * blockDim.x + threadIdx.x;
  if (i >= B * KC * 3) return;
  int b = i / (KC * 3);
  int r = i % (KC * 3);
  centers[i] = x[(size_t)b * N * 3 + r];   // c = x[:, :K, :]
}

// 4 points per thread via 3x float4 loads, packed u32 cl store.
// XCD-affine: batch = blockIdx & 7.
__global__ __launch_bounds__(256)
void k_assign(const float* __restrict__ x, const float* __restrict__ centers,
              unsigned char* __restrict__ cl) {
  __shared__ float4 cs[KC];
  int g = blockIdx.x;
  int b = g & 7;                    // batch -> XCD
  int chunk = g >> 3;               // 0..63
  int t = threadIdx.x;
  if (t < KC) {
    float a0 = centers[(b * KC + t) * 3 + 0];
    float a1 = centers[(b * KC + t) * 3 + 1];
    float a2 = centers[(b * KC + t) * 3 + 2];
    cs[t] = make_float4(a0, a1, a2, sq3(a0, a1, a2));
  }
  __syncthreads();
  int q = chunk * 256 + t;          // quad index (points 4q..4q+3)
  const float4* xb4 = (const float4*)(x + (size_t)b * N * 3);
  float4 A = xb4[3 * q], Bv = xb4[3 * q + 1], C = xb4[3 * q + 2];
  float p0x = A.x, p0y = A.y, p0z = A.z;
  float p1x = A.w, p1y = Bv.x, p1z = Bv.y;
  float p2x = Bv.z, p2y = Bv.w, p2z = C.x;
  float p3x = C.y, p3y = C.z, p3z = C.w;
  float s0 = sq3(p0x, p0y, p0z);
  float s1 = sq3(p1x, p1y, p1z);
  float s2 = sq3(p2x, p2y, p2z);
  float s3 = sq3(p3x, p3y, p3z);
  float inf = __int_as_float(0x7f800000);
  float b0 = inf, b1 = inf, b2 = inf, b3 = inf;
  int i0 = 0, i1 = 0, i2 = 0, i3 = 0;
  for (int k = 0; k < KC; ++k) {
    float4 cc = cs[k];
    float d0 = distf(s0, cc.w, dot3(p0x, p0y, p0z, cc.x, cc.y, cc.z));
    float d1 = distf(s1, cc.w, dot3(p1x, p1y, p1z, cc.x, cc.y, cc.z));
    float d2 = distf(s2, cc.w, dot3(p2x, p2y, p2z, cc.x, cc.y, cc.z));
    float d3 = distf(s3, cc.w, dot3(p3x, p3y, p3z, cc.x, cc.y, cc.z));
    if (d0 < b0) { b0 = d0; i0 = k; }   // first-min == argmin
    if (d1 < b1) { b1 = d1; i1 = k; }
    if (d2 < b2) { b2 = d2; i2 = k; }
    if (d3 < b3) { b3 = d3; i3 = k; }
  }
  *(u32*)(cl + (size_t)b * N + 4 * q) =
      (u32)i0 | ((u32)i1 << 8) | ((u32)i2 << 16) | ((u32)i3 << 24);
}

// one block per (b,k), 1024 threads (R14-verbatim): scan cl (stable
// ascending order), build u16 member list in LDS, gather coords to SoA
// LDS, lanes 0/1/2 run the three sequential fp32 chains (unroll 8) —
// bit-identical to np.add.at per-cluster sequential sum.
__global__ __launch_bounds__(UPD_T)
void k_cluster_update(const float* __restrict__ x, const unsigned char* __restrict__ cl,
                      float* __restrict__ centers) {
  __shared__ u16 midx[RANGE];                 // 32 KB
  __shared__ float bcoord[3][GBATCH + 1];     // ~24 KB, padded stride
  __shared__ int woff[16];
  __shared__ int sCnt;
  int g = blockIdx.x;
  int bk = ((g & 7) << 6) | (g >> 3);         // XCD-affine: batch = g & 7
  int b = bk >> 6, k = bk & 63;
  int t = threadIdx.x, lane = t & 63, wid = t >> 6;
  const unsigned char* clb = cl + (size_t)b * N;
  const float* xb = x + (size_t)b * N * 3;
  float acc = 0.f;      // lanes 0/1/2 of wave 0 carry x/y/z sums
  int cntAll = 0;

  for (int r = 0; r < NRANGE; ++r) {
    // 1. count matches in my contiguous 16-point segment
    const uint4* cp = (const uint4*)(clb + r * RANGE);
    uint4 v = cp[t];
    u32 wsv[4] = {v.x, v.y, v.z, v.w};
    int m = 0;
#pragma unroll
    for (int j = 0; j < PPT; ++j)
      m += (((wsv[j >> 2] >> ((j & 3) * 8)) & 255u) == (u32)k);
    // 2. block exclusive scan of per-thread counts
    int incl = m;
#pragma unroll
    for (int o = 1; o < 64; o <<= 1) {
      int u = __shfl_up(incl, o);
      if (lane >= o) incl += u;
    }
    if (lane == 63) woff[wid] = incl;
    __syncthreads();
    if (t == 0) {
      int run = 0;
      for (int w = 0; w < 16; ++w) { int vv = woff[w]; woff[w] = run; run += vv; }
      sCnt = run;
    }
    __syncthreads();
    int off = woff[wid] + incl - m;
    int mcnt = sCnt;
    // 3. write member local indices in ascending order (stable)
    int base = t * PPT;
#pragma unroll
    for (int j = 0; j < PPT; ++j) {
      if (((wsv[j >> 2] >> ((j & 3) * 8)) & 255u) == (u32)k)
        midx[off++] = (u16)(base + j);
    }
    __syncthreads();
    // 4. gather + lockstep serial sum, in batches
    int rbase = r * RANGE;
    for (int bo = 0; bo < mcnt; bo += GBATCH) {
      int bn = min(GBATCH, mcnt - bo);
      for (int i = t; i < bn; i += UPD_T) {
        int li = rbase + (int)midx[bo + i];
        size_t src = (size_t)li * 3;
        bcoord[0][i] = xb[src];
        bcoord[1][i] = xb[src + 1];
        bcoord[2][i] = xb[src + 2];
      }
      __syncthreads();
      if (t < 3) {
        const float* mb = &bcoord[t][0];
#pragma unroll 8
        for (int i = 0; i < bn; ++i) acc = __fadd_rn(acc, mb[i]);
      }
      __syncthreads();
    }
    cntAll += mcnt;
    __syncthreads();
  }
  if (t < 3)
    centers[bk * 3 + t] = __fdiv_rn(acc, (float)cntAll);
}

// ---- top-k stage 1: per-(b,k) EXACT sample threshold ----
__global__ __launch_bounds__(256)
void k_thresh(const float* __restrict__ x, const float* __restrict__ centers,
              u32* __restrict__ thr, u32* __restrict__ cnt) {
  __shared__ u32 whist[4 * HPAD];
  __shared__ int sv[256];
  __shared__ u32 skeys[SCAP];
  __shared__ float4 scen;
  __shared__ u32 sSel;
  __shared__ int sNeed, sCntBin, sNum;
  int g = blockIdx.x;
  int bk = ((g & 7) << 6) | (g >> 3);   // XCD-affine
  int b = bk >> 6;
  int t = threadIdx.x, wid = t >> 6;
  if (t == 0) {
    float c0 = centers[bk * 3], c1 = centers[bk * 3 + 1], c2 = centers[bk * 3 + 2];
    scen = make_float4(c0, c1, c2, sq3(c0, c1, c2));
    cnt[bk * CSTRIDE] = 0;
    sNum = 0;
  }
  for (int i = t; i < 4 * HPAD; i += 256) whist[i] = 0;
  __syncthreads();
  float c0 = scen.x, c1 = scen.y, c2 = scen.z, d2 = scen.w;
  const float2* xb2 = (const float2*)(x + (size_t)b * N * 3);

  for (int p = t; p < SAMPLE / 2; p += 256) {
    float2 A = xb2[3 * p], Bv = xb2[3 * p + 1], C = xb2[3 * p + 2];
    float d0 = distf(sq3(A.x, A.y, Bv.x), d2, dot3(A.x, A.y, Bv.x, c0, c1, c2));
    float d1 = distf(sq3(Bv.y, C.x, C.y), d2, dot3(Bv.y, C.x, C.y, c0, c1, c2));
    atomicAdd(&whist[wid * HPAD + (fkey(d0) >> 24)], 1u);
    atomicAdd(&whist[wid * HPAD + (fkey(d1) >> 24)], 1u);
  }
  __syncthreads();
  int own = (int)(whist[0 * HPAD + t] + whist[1 * HPAD + t] +
                  whist[2 * HPAD + t] + whist[3 * HPAD + t]);
  sv[t] = own;
  __syncthreads();
  for (int off = 1; off < 256; off <<= 1) {
    int add = (t >= off) ? sv[t - off] : 0;
    __syncthreads();
    sv[t] += add;
    __syncthreads();
  }
  if (sv[t] >= M && sv[t] - own < M) {
    sSel = (u32)t; sNeed = M - (sv[t] - own); sCntBin = own;
  }
  __syncthreads();
  u32 selByte = sSel;
  int need = sNeed;
  int cntBin = sCntBin;
  u32 prefix = selByte << 24;

  if (cntBin <= SCAP) {
    for (int p = t; p < SAMPLE / 2; p += 256) {
      float2 A = xb2[3 * p], Bv = xb2[3 * p + 1], C = xb2[3 * p + 2];
      float d0 = distf(sq3(A.x, A.y, Bv.x), d2, dot3(A.x, A.y, Bv.x, c0, c1, c2));
      float d1 = distf(sq3(Bv.y, C.x, C.y), d2, dot3(Bv.y, C.x, C.y, c0, c1, c2));
      u32 k0 = fkey(d0), k1 = fkey(d1);
      if ((k0 >> 24) == selByte) skeys[atomicAdd(&sNum, 1)] = k0;
      if ((k1 >> 24) == selByte) skeys[atomicAdd(&sNum, 1)] = k1;
    }
    __syncthreads();
    int ne = sNum;
    for (int sh = 16; sh >= 0; sh -= 8) {
      whist[t] = 0;
      __syncthreads();
      for (int i = t; i < ne; i += 256) {
        u32 kkk = skeys[i];
        if ((kkk >> (sh + 8)) == (prefix >> (sh + 8)))
          atomicAdd(&whist[(kkk >> sh) & 255u], 1u);
      }
      __syncthreads();
      int own2 = (int)whist[t];
      sv[t] = own2;
      __syncthreads();
      for (int off = 1; off < 256; off <<= 1) {
        int add = (t >= off) ? sv[t - off] : 0;
        __syncthreads();
        sv[t] += add;
        __syncthreads();
      }
      if (sv[t] >= need && sv[t] - own2 < need) {
        sSel = prefix | ((u32)t << sh);
        sNeed = need - (sv[t] - own2);
      }
      __syncthreads();
      prefix = sSel; need = sNeed;
      __syncthreads();
    }
    if (t == 0) thr[bk] = prefix;
  } else {
    if (t == 0) thr[bk] = prefix | 0x00FFFFFFu;
  }
}

// ---- top-k stage 2: one shared pass, ballot-aggregated reservation ----
__global__ __launch_bounds__(256)
void k_scatter_test(const float* __restrict__ x, const float* __restrict__ centers,
                    const u32* __restrict__ thr, u32* __restrict__ cnt,
                    u32* __restrict__ cand) {
  __shared__ float4 cs[KC];
  __shared__ u32 lthr[KC];
  __shared__ u64 wm0[4][KC], wm1[4][KC];
  __shared__ u32 wbase[4][KC];
  int g = blockIdx.x;
  int b = g & 7;
  int chunk = g >> 3;
  int t = threadIdx.x, lane = t & 63, wid = t >> 6;
  if (t < KC) {
    float a0 = centers[(b * KC + t) * 3 + 0];
    float a1 = centers[(b * KC + t) * 3 + 1];
    float a2 = centers[(b * KC + t) * 3 + 2];
    cs[t] = make_float4(a0, a1, a2, sq3(a0, a1, a2));
    lthr[t] = thr[b * KC + t];
  }
  __syncthreads();
  int pr = chunk * 256 + t;
  const float2* xb2 = (const float2*)(x + (size_t)b * N * 3);
  float2 A = xb2[3 * pr], Bv = xb2[3 * pr + 1], C = xb2[3 * pr + 2];
  float s20 = sq3(A.x, A.y, Bv.x);
  float s21 = sq3(Bv.y, C.x, C.y);
  u32 n0 = 2 * pr, n1 = 2 * pr + 1;
  u64 ltm = ((u64)1 << lane) - 1;

  for (int k = 0; k < KC; ++k) {
    float4 cc = cs[k];
    float d0 = distf(s20, cc.w, dot3(A.x, A.y, Bv.x, cc.x, cc.y, cc.z));
    float d1 = distf(s21, cc.w, dot3(Bv.y, C.x, C.y, cc.x, cc.y, cc.z));
    u64 m0 = __ballot(fkey(d0) <= lthr[k]);
    u64 m1 = __ballot(fkey(d1) <= lthr[k]);
    if (lane == 0) { wm0[wid][k] = m0; wm1[wid][k] = m1; }
  }
  __syncthreads();
  if (t < KC) {
    u32 pc[4];
    u32 total = 0;
#pragma unroll
    for (int w = 0; w < 4; ++w) {
      pc[w] = (u32)(__popcll(wm0[w][t]) + __popcll(wm1[w][t]));
      total += pc[w];
    }
    u32 base = (total > 0) ? atomicAdd(&cnt[(b * KC + t) * CSTRIDE], total) : 0u;
#pragma unroll
    for (int w = 0; w < 4; ++w) { wbase[w][t] = base; base += pc[w]; }
  }
  __syncthreads();
  u64 mybit = (u64)1 << lane;
  for (int k = 0; k < KC; ++k) {
    u64 m0 = wm0[wid][k], m1 = wm1[wid][k];
    if ((m0 | m1) == 0) continue;
    u32 wb = wbase[wid][k];
    u32* cb = cand + (size_t)(b * KC + k) * CAPG;
    if (m0 & mybit) {
      u32 pos = wb + (u32)__popcll(m0 & ltm);
      if (pos < CAPG) cb[pos] = n0;
    }
    if (m1 & mybit) {
      u32 pos = wb + (u32)__popcll(m0) + (u32)__popcll(m1 & ltm);
      if (pos < CAPG) cb[pos] = n1;
    }
  }
}

// ---- top-k stage 3: radix-select exact 128th key, sort winners ----
__global__ __launch_bounds__(256)
void k_topk_sort(const float* __restrict__ x, const float* __restrict__ centers,
                 const u32* __restrict__ cnt, const u32* __restrict__ cand,
                 float* __restrict__ neighbor) {
  __shared__ u64 candList[CAPG];
  __shared__ u32 hist[256];
  __shared__ u64 wbuf[WCAP];
  __shared__ u64 lessList[M];
  __shared__ u32 eqList[256];
  __shared__ u32 sSel;
  __shared__ int sNeed;
  __shared__ int cntW, cntLess, cntEq;
  __shared__ float4 scen;
  int g = blockIdx.x;
  int bk = ((g & 7) << 6) | (g >> 3);
  int b = bk >> 6;
  int t = threadIdx.x, lane = t & 63, wid = t >> 6;
  if (t == 0) {
    float c0 = centers[bk * 3], c1 = centers[bk * 3 + 1], c2 = centers[bk * 3 + 2];
    scen = make_float4(c0, c1, c2, sq3(c0, c1, c2));
    cntW = 0;
  }
  __syncthreads();
  float c0 = scen.x, c1 = scen.y, c2 = scen.z, d2 = scen.w;
  const float* xb = x + (size_t)b * N * 3;
  int cc = (int)cnt[bk * CSTRIDE];

  if (cc <= CAPG) {
    const u32* cb = cand + (size_t)bk * CAPG;
    for (int i = t; i < cc; i += 256) {
      u32 n = cb[i];
      float x0 = xb[n * 3], x1 = xb[n * 3 + 1], x2 = xb[n * 3 + 2];
      float d = distf(sq3(x0, x1, x2), d2, dot3(x0, x1, x2, c0, c1, c2));
      candList[i] = ((u64)fkey(d) << 32) | n;
    }
    __syncthreads();
    u32 prefix = 0;
    int need = M;
    for (int r = 3; r >= 0; --r) {
      int sh = r * 8;
      hist[t] = 0;
      __syncthreads();
      for (int i = t; i < cc; i += 256) {
        u32 key = (u32)(candList[i] >> 32);
        bool ok = (r == 3) || ((key >> (sh + 8)) == (prefix >> (sh + 8)));
        if (ok) atomicAdd(&hist[(key >> sh) & 255u], 1u);
      }
      __syncthreads();
      if (wid == 0) {
        u32 h0 = hist[4 * lane + 0], h1 = hist[4 * lane + 1];
        u32 h2 = hist[4 * lane + 2], h3 = hist[4 * lane + 3];
        u32 lsum = h0 + h1 + h2 + h3;
        u32 incl = lsum;
#pragma unroll
        for (int o = 1; o < 64; o <<= 1) {
          u32 u = __shfl_up(incl, o);
          if (lane >= o) incl += u;
        }
        u32 excl = incl - lsum;
        if ((int)excl < need && need <= (int)incl) {
          u32 hh[4] = {h0, h1, h2, h3};
          u32 cum = excl; int bin = -1; u32 bc = 0;
#pragma unroll
          for (int j = 0; j < 4; ++j) {
            if (bin < 0 && (int)(cum + hh[j]) >= need) { bin = 4 * lane + j; bc = cum; }
            cum += hh[j];
          }
          sSel = prefix | ((u32)bin << sh);
          sNeed = need - (int)bc;
        }
      }
      __syncthreads();
      prefix = sSel; need = sNeed;
      __syncthreads();
    }
    u32 K128 = prefix;
    for (int i = t; i < cc; i += 256) {
      u64 e = candList[i];
      if ((u32)(e >> 32) <= K128) {
        int p = atomicAdd(&cntW, 1);
        if (p < WCAP) wbuf[p] = e;
      }
    }
    __syncthreads();
    int wcnt2 = cntW;
    if (wcnt2 <= WCAP) {
      for (int i = t; i < WCAP; i += 256) if (i >= wcnt2) wbuf[i] = ~0ull;
      __syncthreads();
      for (int ksz = 2; ksz <= WCAP; ksz <<= 1) {
        for (int j = ksz >> 1; j > 0; j >>= 1) {
          for (int idx = t; idx < WCAP; idx += 256) {
            int ixj = idx ^ j;
            if (ixj > idx) {
              u64 a = wbuf[idx], bb = wbuf[ixj];
              bool up = ((idx & ksz) == 0);
              if (up ? (a > bb) : (a < bb)) { wbuf[idx] = bb; wbuf[ixj] = a; }
            }
          }
          __syncthreads();
        }
      }
      if (t < M) {
        int idx = (int)(wbuf[t] & 0xFFFFFFFFu);
        size_t src = ((size_t)b * N + idx) * 3;
        size_t dst = ((size_t)bk * M + t) * 3;
        neighbor[dst]     = x[src];
        neighbor[dst + 1] = x[src + 1];
        neighbor[dst + 2] = x[src + 2];
      }
      return;
    }
  }

  // ---- fallback: full byte-radix over N (bit-identical, rare) ----
  if (t == 0) { cntLess = 0; cntEq = 0; }
  __syncthreads();
  u32 prefix = 0;
  int need = M;
  for (int r = 3; r >= 0; --r) {
    for (int i = t; i < 256; i += 256) hist[i] = 0;
    __syncthreads();
    int sh = r * 8;
    for (int n = t; n < N; n += 256) {
      float x0 = xb[n * 3], x1 = xb[n * 3 + 1], x2 = xb[n * 3 + 2];
      float d = distf(sq3(x0, x1, x2), d2, dot3(x0, x1, x2, c0, c1, c2));
      u32 key = fkey(d);
      bool ok = (r == 3) || ((key >> (sh + 8)) == (prefix >> (sh + 8)));
      if (ok) atomicAdd(&hist[(key >> sh) & 255u], 1u);
    }
    __syncthreads();
    if (t == 0) {
      int cum = 0;
      for (int bin = 0; bin < 256; ++bin) {
        int ccv = (int)hist[bin];
        if (cum + ccv >= need) { sSel = prefix | ((u32)bin << sh); sNeed = need - cum; break; }
        cum += ccv;
      }
    }
    __syncthreads();
    prefix = sSel; need = sNeed;
    __syncthreads();
  }
  u32 K128 = prefix;

  for (int n = t; n < N; n += 256) {
    float x0 = xb[n * 3], x1 = xb[n * 3 + 1], x2 = xb[n * 3 + 2];
    float d = distf(sq3(x0, x1, x2), d2, dot3(x0, x1, x2, c0, c1, c2));
    u32 key = fkey(d);
    if (key < K128) {
      int p = atomicAdd(&cntLess, 1);
      if (p < M) lessList[p] = ((u64)key << 32) | (u32)n;
    } else if (key == K128) {
      int p = atomicAdd(&cntEq, 1);
      if (p < 256) eqList[p] = (u32)n;
    }
  }
  __syncthreads();
  int nl = cntLess;
  int ne2 = cntEq;
  for (int i = t; i < M; i += 256) if (i >= nl) lessList[i] = ~0ull;
  for (int i = t; i < 256; i += 256) if (i >= ne2) eqList[i] = 0xFFFFFFFFu;
  __syncthreads();

  for (int ksz = 2; ksz <= M; ksz <<= 1) {
    for (int j = ksz >> 1; j > 0; j >>= 1) {
      for (int idx = t; idx < M; idx += 256) {
        int ixj = idx ^ j;
        if (ixj > idx) {
          u64 a = lessList[idx], bb = lessList[ixj];
          bool up = ((idx & ksz) == 0);
          if (up ? (a > bb) : (a < bb)) { lessList[idx] = bb; lessList[ixj] = a; }
        }
      }
      __syncthreads();
    }
  }
  for (int ksz = 2; ksz <= 256; ksz <<= 1) {
    for (int j = ksz >> 1; j > 0; j >>= 1) {
      for (int idx = t; idx < 256; idx += 256) {
        int ixj = idx ^ j;
        if (ixj > idx) {
          u32 a = eqList[idx], bb = eqList[ixj];
          bool up = ((idx & ksz) == 0);
          if (up ? (a > bb) : (a < bb)) { eqList[idx] = bb; eqList[ixj] = a; }
        }
      }
      __syncthreads();
    }
  }

  if (t < M) {
    int idx = (t < nl) ? (int)(lessList[t] & 0xFFFFFFFFu) : (int)eqList[t - nl];
    size_t src = ((size_t)b * N + idx) * 3;
    size_t dst = ((size_t)bk * M + t) * 3;
    neighbor[dst]     = x[src];
    neighbor[dst + 1] = x[src + 1];
    neighbor[dst + 2] = x[src + 2];
  }
}

// wave-synchronous FPS: 1 wave per group, 2 points/lane, packed-u64
// shfl_xor argmax (first-occurrence tiebreak), zero in-loop barriers.
__global__ __launch_bounds__(64)
void k_fps(const float* __restrict__ neighbor, const int* __restrict__ farthest0,
           const float* __restrict__ centers, float* __restrict__ out) {
  __shared__ float4 pts[M];
  int bg = blockIdx.x;
  int b = bg >> 6, g = bg & 63;
  int t = threadIdx.x;
  {
    int i = bg * 64 + t;
    if (i < B * KC * 3) out[B * 4096 * 3 + i] = centers[i];
  }
  const float* nb = neighbor + (size_t)bg * M * 3;
  float ax = nb[6 * t],     ay = nb[6 * t + 1], az = nb[6 * t + 2];
  float bx = nb[6 * t + 3], by = nb[6 * t + 4], bz = nb[6 * t + 5];
  pts[2 * t]     = make_float4(ax, ay, az, 0.f);
  pts[2 * t + 1] = make_float4(bx, by, bz, 0.f);
  int far = farthest0[bg];
  float dist0 = 1e10f, dist1 = 1e10f;
  __syncthreads();
  float* ob = out + ((size_t)b * 4096 + g * 64) * 3;
  for (int s = 0; s < S; ++s) {
    if ((far >> 1) == t) {
      if (far & 1) { ob[3 * s] = bx; ob[3 * s + 1] = by; ob[3 * s + 2] = bz; }
      else         { ob[3 * s] = ax; ob[3 * s + 1] = ay; ob[3 * s + 2] = az; }
    }
    float4 cc = pts[far];
    float d0 = sq3(__fsub_rn(ax, cc.x), __fsub_rn(ay, cc.y), __fsub_rn(az, cc.z));
    float d1 = sq3(__fsub_rn(bx, cc.x), __fsub_rn(by, cc.y), __fsub_rn(bz, cc.z));
    dist0 = fminf(dist0, d0);
    dist1 = fminf(dist1, d1);
    u64 k0 = ((u64)__float_as_uint(dist0) << 32) | (u32)(M - 1 - 2 * t);
    u64 k1 = ((u64)__float_as_uint(dist1) << 32) | (u32)(M - 2 - 2 * t);
    u64 key = (k0 > k1) ? k0 : k1;
#pragma unroll
    for (int off = 1; off < 64; off <<= 1) {
      u64 o = __shfl_xor(key, off);
      if (o > key) key = o;
    }
    far = M - 1 - (int)(key & 0xFFFFFFFFu);
  }
}

extern "C" void kernel_launch(void* const* d_in, const int* in_sizes, int n_in,
                              void* d_out, int out_size, void* d_ws, size_t ws_size,
                              hipStream_t stream) {
  const float* x = (const float*)d_in[0];
  const int* farthest0 = (const int*)d_in[1];
  float* out = (float*)d_out;

  char* w = (char*)d_ws;
  float* centers  = (float*)(w);                               // 8 KB slot
  unsigned char* cl = (unsigned char*)(w + 8192);              // 512 KB
  u32* thr        = (u32*)(w + 8192 + 524288);                 // 4 KB slot
  u32* cnt        = (u32*)(w + 8192 + 524288 + 4096);          // 64 KB (strided)
  float* neighbor = (float*)(w + 8192 + 524288 + 4096 + 65536);            // 768 KB
  u32* cand       = (u32*)(w + 8192 + 524288 + 4096 + 65536 + 786432);     // 6 MB
  // total ws use ≈ 7.4 MB

  k_init_centers<<<6, 256, 0, stream>>>(x, centers);
  for (int it = 0; it < NITER; ++it) {
    k_assign<<<B * NCHK, 256, 0, stream>>>(x, centers, cl);
    k_cluster_update<<<B * KC, UPD_T, 0, stream>>>(x, cl, centers);
  }
  k_thresh<<<B * KC, 256, 0, stream>>>(x, centers, thr, cnt);
  k_scatter_test<<<B * NCHK * 2, 256, 0, stream>>>(x, centers, thr, cnt, cand);
  k_topk_sort<<<B * KC, 256, 0, stream>>>(x, centers, cnt, cand, neighbor);
  k_fps<<<B * KC, M / 2, 0, stream>>>(neighbor, farthest0, centers, out);
}